// Round 14
// baseline (263.594 us; speedup 1.0000x reference)
//
#include <hip/hip_runtime.h>
#include <hip/hip_bf16.h>
#include <math.h>

#define GG 8192      // graphs = B*T
#define NODESN 23
#define KK 8
#define DIN 16
#define HH 128
#define RHH 128
#define EPG (NODESN*KK)   // 184 edges per graph
#define TTT 128
#define BBB 64

typedef float v2f __attribute__((ext_vector_type(2)));

// ---------------------------------------------------------------------------
// DPP cross-lane add (VALU pipe -- NOT the DS pipe, unlike __shfl_xor).
// ---------------------------------------------------------------------------
template<int CTRL>
static __device__ __forceinline__ float dpp_add(float v) {
    int x = __builtin_amdgcn_update_dpp(0, __float_as_int(v), CTRL, 0xF, 0xF, true);
    return v + __int_as_float(x);
}
#define DPP_XOR1 0xB1   // quad_perm [1,0,3,2]
#define DPP_XOR2 0x4E   // quad_perm [2,3,0,1]
#define DPP_HMIR 0x141  // row_half_mirror: lane low-3 bits mirrored (q -> 7-q)

// ---------------------------------------------------------------------------
// Kernel 1: per-graph GCN up to hsum -> xg[g*384 + 0..127] (dead space reuse).
// ---------------------------------------------------------------------------
__global__ __launch_bounds__(256) void gcn_hsum(
    const float* __restrict__ x, const int* __restrict__ esrc,
    const int* __restrict__ runner,
    const float* __restrict__ W1, const float* __restrict__ b1,
    float* __restrict__ xg)
{
    __shared__ float xs[NODESN * DIN];
    __shared__ int   srcs[EPG];
    __shared__ float t1[NODESN * HH];
    __shared__ float red[256];

    const int g   = blockIdx.x;
    const int tid = threadIdx.x;
    const int j   = tid & 127;
    const int nh  = tid >> 7;

    for (int i = tid; i < NODESN * DIN; i += 256) xs[i] = x[g * NODESN * DIN + i];
    for (int i = tid; i < EPG; i += 256)          srcs[i] = esrc[g * EPG + i] - g * NODESN;

    float w[DIN];
    #pragma unroll
    for (int k = 0; k < DIN; k++) w[k] = W1[k * HH + j];
    const float b1j = b1[j];
    __syncthreads();

    const int n0 = nh * 12;
    const int n1 = nh ? NODESN : 12;
    for (int n = n0; n < n1; n++) {
        float acc = 0.f;
        #pragma unroll
        for (int k = 0; k < DIN; k += 4) {
            float4 xv = *(const float4*)&xs[n * DIN + k];
            acc = fmaf(xv.x, w[k], fmaf(xv.y, w[k+1], fmaf(xv.z, w[k+2], fmaf(xv.w, w[k+3], acc))));
        }
        t1[n * HH + j] = acc;
    }
    __syncthreads();

    const int r = runner[g];
    float part = 0.f;
    for (int slot = nh; slot < 9; slot += 2) {
        int node = (slot < 8) ? srcs[r * KK + slot] : r;
        float acc = t1[node * HH + j];
        #pragma unroll
        for (int k = 0; k < KK; k++) acc += t1[srcs[node * KK + k] * HH + j];
        part += fmaxf(acc * (1.f / 9.f) + b1j, 0.f);
    }
    red[tid] = part;
    __syncthreads();
    if (tid < HH) xg[(size_t)g * 384 + tid] = red[tid] + red[tid + 128];
}

// ---------------------------------------------------------------------------
// Kernel 2: pack W_ih [384,128] -> WTp [k/4][384][4] for b128 column loads.
// ---------------------------------------------------------------------------
__global__ void pack_wih(const float* __restrict__ W, float* __restrict__ WTp)
{
    int idx = blockIdx.x * 256 + threadIdx.x;
    if (idx < 3 * RHH * RHH) {
        int j = idx / RHH, k = idx - j * RHH;
        WTp[(k >> 2) * (384 * 4) + j * 4 + (k & 3)] = W[idx];
    }
}

// ---------------------------------------------------------------------------
// Kernel 3 (fused seq+xg): 16 graphs per block, 384 threads.
// ---------------------------------------------------------------------------
__global__ __launch_bounds__(384) void seqxg_kernel(
    float* __restrict__ xg, const float* __restrict__ W2,
    const float* __restrict__ b2, const float* __restrict__ WTp,
    const float* __restrict__ b_ih)
{
    __shared__ float hsb[16 * HH];
    __shared__ float sqb[16 * HH];
    const int tid = threadIdx.x;
    const size_t row0 = (size_t)blockIdx.x * 16;

    for (int v = tid; v < 16 * 32; v += 384) {
        int m = v >> 5, e = v & 31;
        ((float4*)hsb)[m * 32 + e] = *(const float4*)&xg[(row0 + m) * 384 + e * 4];
    }
    __syncthreads();

    {
        const int j = tid & 127, m0 = tid >> 7;
        const int nm = (m0 == 0) ? 6 : 5;
        float acc[6];
        #pragma unroll
        for (int t = 0; t < 6; t++) acc[t] = 0.f;
        for (int k = 0; k < HH; k += 4) {
            float w0 = W2[(k+0)*HH + j];
            float w1 = W2[(k+1)*HH + j];
            float w2 = W2[(k+2)*HH + j];
            float w3 = W2[(k+3)*HH + j];
            #pragma unroll
            for (int t = 0; t < 6; t++) {
                if (t < nm) {
                    float4 hv = *(const float4*)&hsb[(m0 + 3*t) * HH + k];
                    acc[t] = fmaf(hv.x, w0, fmaf(hv.y, w1, fmaf(hv.z, w2, fmaf(hv.w, w3, acc[t]))));
                }
            }
        }
        const float bj = b2[j];
        for (int t = 0; t < nm; t++)
            sqb[(m0 + 3*t) * HH + j] = fmaxf(acc[t] * (1.f/9.f) + bj, 0.f);
    }
    __syncthreads();

    {
        const int j2 = tid;
        float acc[16];
        const float bv = b_ih[j2];
        #pragma unroll
        for (int m = 0; m < 16; m++) acc[m] = bv;
        for (int k4 = 0; k4 < 32; k4++) {
            float4 wv = *(const float4*)&WTp[k4 * (384*4) + j2 * 4];
            #pragma unroll
            for (int m = 0; m < 16; m++) {
                float4 hv = *(const float4*)&sqb[m * HH + k4 * 4];
                acc[m] = fmaf(hv.x, wv.x, fmaf(hv.y, wv.y, fmaf(hv.z, wv.z, fmaf(hv.w, wv.w, acc[m]))));
            }
        }
        #pragma unroll
        for (int m = 0; m < 16; m++)
            xg[(row0 + m) * 384 + j2] = acc[m];
    }
}

// ---------------------------------------------------------------------------
// Kernel 4: GRU -- R13 base; h-read DS volume halved via 2-units/thread.
// Thread (u,q): q = tid&7 (16-float k-slice), u = tid>>3 -> units 2u, 2u+1
// (96 weight floats/thread, same resident count as R13). Per CU per step:
// 32 h ds_read_b128 (was 64) + 16 xg + 8 b64 writes = ~56 DS instr (was ~80).
// Bank-freedom: even/odd q in disjoint bank halves; (q>>1) phase rotation
// gives the 4 aliasing q-groups disjoint 4-bank sub-blocks.
// 8-lane reduction: DPP xor1 + xor2 + row_half_mirror (pure VALU).
// xg double-buffered one step ahead in registers.
// ---------------------------------------------------------------------------
#define CHUNK 32
#define NCH (TTT / CHUNK)
#define HPAD 132
#define XGB_FLOATS (CHUNK * HH * 4)      // 16384 floats = 64 KB

__global__ __launch_bounds__(512)
__attribute__((amdgpu_waves_per_eu(2, 2)))
void gru_kernel(
    const float* __restrict__ xg, const float* __restrict__ W_hh,
    const float* __restrict__ b_hh, const float* __restrict__ Wp,
    const float* __restrict__ bp, float* __restrict__ out)
{
    __shared__ float xgbuf[XGB_FLOATS];          // [tl][i][{xr,xz,xn,pad}]
    __shared__ float houtb[(CHUNK + 1) * HPAD];  // row 0 = carry; rows 1..32 = h(t)
    __shared__ float wps[2 * RHH + 2];           // Wp + bp
    // 64K + 17K + 1K = 82.4 KB -> exactly 1 block/CU

    const int b   = blockIdx.x;
    const int tid = threadIdx.x;
    const int q   = tid & 7;       // k-eighth (lane bits 0..2)
    const int u   = tid >> 3;      // unit pair 0..63 -> units 2u, 2u+1

    const int i0 = 2 * u, i1 = 2 * u + 1;

    // ---- preload W_hh: rows {i0,i1} x {r,z,n}, cols [16q,16q+16),
    // phase p = (m + (q>>1)) & 3 -> the 4 bank-aliasing q-groups read
    // disjoint 4-bank sub-blocks. Stored as v2f for v_pk_fma_f32.
    v2f wr0[8], wz0[8], wn0[8], wr1[8], wz1[8], wn1[8];
    int lof[4];
    {
        const float* r0 = W_hh + (size_t)i0 * RHH;
        const float* z0 = r0 + (size_t)RHH * RHH;
        const float* n0 = z0 + (size_t)RHH * RHH;
        const float* r1 = W_hh + (size_t)i1 * RHH;
        const float* z1 = r1 + (size_t)RHH * RHH;
        const float* n1 = z1 + (size_t)RHH * RHH;
        #pragma unroll
        for (int m = 0; m < 4; m++) {
            int p = (m + (q >> 1)) & 3;
            int o = q * 16 + 4 * p;
            lof[m] = o;
            float4 v;
            v = *(const float4*)(r0 + o); wr0[2*m] = (v2f){v.x,v.y}; wr0[2*m+1] = (v2f){v.z,v.w};
            v = *(const float4*)(z0 + o); wz0[2*m] = (v2f){v.x,v.y}; wz0[2*m+1] = (v2f){v.z,v.w};
            v = *(const float4*)(n0 + o); wn0[2*m] = (v2f){v.x,v.y}; wn0[2*m+1] = (v2f){v.z,v.w};
            v = *(const float4*)(r1 + o); wr1[2*m] = (v2f){v.x,v.y}; wr1[2*m+1] = (v2f){v.z,v.w};
            v = *(const float4*)(z1 + o); wz1[2*m] = (v2f){v.x,v.y}; wz1[2*m+1] = (v2f){v.z,v.w};
            v = *(const float4*)(n1 + o); wn1[2*m] = (v2f){v.x,v.y}; wn1[2*m+1] = (v2f){v.z,v.w};
        }
    }
    const float bhr0 = b_hh[i0], bhz0 = b_hh[RHH + i0], bhn0 = b_hh[2 * RHH + i0];
    const float bhr1 = b_hh[i1], bhz1 = b_hh[RHH + i1], bhn1 = b_hh[2 * RHH + i1];

    if (tid < 2 * RHH) wps[tid] = Wp[tid];
    if (tid < 2)       wps[2 * RHH + tid] = bp[tid];
    if (tid < HH)      houtb[tid] = 0.f;          // carry row 0 = h(-1) = 0
    float hp0 = 0.f, hp1 = 0.f;

    const float* xbase = xg + (size_t)b * TTT * 3 * RHH;
    float* outb = out + (size_t)b * TTT * 2;

    for (int c = 0; c < NCH; c++) {
        // ---- refill xgbuf for chunk c, repacking to [tl][i][{r,z,n,pad}]
        #pragma unroll
        for (int k2 = 0; k2 < 8; k2++) {
            int slot = tid + (k2 << 9);          // 0..4095
            int tl = slot >> 7, ii = slot & 127;
            const float* gsrc = xbase + (size_t)(c * CHUNK + tl) * 384 + ii;
            float4 v;
            v.x = gsrc[0]; v.y = gsrc[128]; v.z = gsrc[256]; v.w = 0.f;
            *(float4*)&xgbuf[slot << 2] = v;
        }
        // ---- project previous chunk: out = houtb[1..32] @ Wp + bp
        if (c > 0) {
            const int s  = tid & 3;              // 32-float k-slice (quad domain)
            const int cc = (tid >> 2) & 1;
            const int tl = tid >> 3;             // 0..63 -> guard to 0..31
            if (tl < CHUNK) {
                const float* hr = &houtb[(tl + 1) * HPAD + s * 32];
                float acc = 0.f;
                #pragma unroll
                for (int jj = 0; jj < 8; jj++) {
                    int mm = 4 * ((jj + 2 * s) & 7);
                    float4 hv = *(const float4*)(hr + mm);
                    int k = s * 32 + mm;
                    acc = fmaf(hv.x, wps[(k+0)*2 + cc],
                          fmaf(hv.y, wps[(k+1)*2 + cc],
                          fmaf(hv.z, wps[(k+2)*2 + cc],
                          fmaf(hv.w, wps[(k+3)*2 + cc], acc))));
                }
                acc = dpp_add<DPP_XOR1>(acc);
                acc = dpp_add<DPP_XOR2>(acc);
                if (s == 0)
                    outb[((c - 1) * CHUNK + tl) * 2 + cc] = acc + wps[2 * RHH + cc];
            }
        }
        __syncthreads();

        // ---- prime xg regs for step 0 of this chunk
        float4 x0 = *(const float4*)&xgbuf[(0 * HH + i0) << 2];
        float4 x1 = *(const float4*)&xgbuf[(0 * HH + i1) << 2];

        // ---- 32 steps; per CU per step: 32 h b128 + 16 xg b128 + 8 b64 wr
        for (int tl = 0; tl < CHUNK; tl++) {
            const float* hrow = &houtb[tl * HPAD];
            v2f ar0v = (v2f){0.f,0.f}, az0v = ar0v, an0v = ar0v;
            v2f ar1v = ar0v, az1v = ar0v, an1v = ar0v;
            #pragma unroll
            for (int m = 0; m < 4; m++) {
                float4 hv = *(const float4*)(hrow + lof[m]);
                v2f h0 = (v2f){hv.x, hv.y};
                v2f h1 = (v2f){hv.z, hv.w};
                ar0v = h0 * wr0[2*m] + ar0v; ar0v = h1 * wr0[2*m+1] + ar0v;
                az0v = h0 * wz0[2*m] + az0v; az0v = h1 * wz0[2*m+1] + az0v;
                an0v = h0 * wn0[2*m] + an0v; an0v = h1 * wn0[2*m+1] + an0v;
                ar1v = h0 * wr1[2*m] + ar1v; ar1v = h1 * wr1[2*m+1] + ar1v;
                az1v = h0 * wz1[2*m] + az1v; az1v = h1 * wz1[2*m+1] + az1v;
                an1v = h0 * wn1[2*m] + an1v; an1v = h1 * wn1[2*m+1] + an1v;
            }
            float ar0 = ar0v.x + ar0v.y, az0 = az0v.x + az0v.y, an0 = an0v.x + an0v.y;
            float ar1 = ar1v.x + ar1v.y, az1 = az1v.x + az1v.y, an1 = an1v.x + an1v.y;

            // prefetch next step's xg (no dependency on h(t+1))
            float4 nx0, nx1;
            if (tl + 1 < CHUNK) {
                nx0 = *(const float4*)&xgbuf[((tl + 1) * HH + i0) << 2];
                nx1 = *(const float4*)&xgbuf[((tl + 1) * HH + i1) << 2];
            }

            // 8-lane q-reduction: xor1 + xor2 + half-mirror (pure VALU)
            ar0 = dpp_add<DPP_XOR1>(ar0); ar0 = dpp_add<DPP_XOR2>(ar0); ar0 = dpp_add<DPP_HMIR>(ar0);
            az0 = dpp_add<DPP_XOR1>(az0); az0 = dpp_add<DPP_XOR2>(az0); az0 = dpp_add<DPP_HMIR>(az0);
            an0 = dpp_add<DPP_XOR1>(an0); an0 = dpp_add<DPP_XOR2>(an0); an0 = dpp_add<DPP_HMIR>(an0);
            ar1 = dpp_add<DPP_XOR1>(ar1); ar1 = dpp_add<DPP_XOR2>(ar1); ar1 = dpp_add<DPP_HMIR>(ar1);
            az1 = dpp_add<DPP_XOR1>(az1); az1 = dpp_add<DPP_XOR2>(az1); az1 = dpp_add<DPP_HMIR>(az1);
            an1 = dpp_add<DPP_XOR1>(an1); an1 = dpp_add<DPP_XOR2>(an1); an1 = dpp_add<DPP_HMIR>(an1);

            // gates for both units (uniform across q-lanes); q==0 publishes
            {
                float sr = x0.x + ar0 + bhr0;
                float sz = x0.y + az0 + bhz0;
                float rg = 1.f / (1.f + __expf(-sr));
                float zg = 1.f / (1.f + __expf(-sz));
                float tv = fmaf(rg, an0 + bhn0, x0.z);
                tv = fminf(fmaxf(tv, -15.f), 15.f);
                float e2 = __expf(-2.f * tv);
                float ng = (1.f - e2) / (1.f + e2);
                hp0 = fmaf(zg, hp0, (1.f - zg) * ng);
            }
            {
                float sr = x1.x + ar1 + bhr1;
                float sz = x1.y + az1 + bhz1;
                float rg = 1.f / (1.f + __expf(-sr));
                float zg = 1.f / (1.f + __expf(-sz));
                float tv = fmaf(rg, an1 + bhn1, x1.z);
                tv = fminf(fmaxf(tv, -15.f), 15.f);
                float e2 = __expf(-2.f * tv);
                float ng = (1.f - e2) / (1.f + e2);
                hp1 = fmaf(zg, hp1, (1.f - zg) * ng);
            }
            if (q == 0) {
                float2 hw; hw.x = hp0; hw.y = hp1;
                *(float2*)&houtb[(tl + 1) * HPAD + i0] = hw;
            }
            x0 = nx0; x1 = nx1;
            __syncthreads();
        }
        // carry: last h of this chunk becomes row 0 for the next
        if (q == 0) {
            float2 hw; hw.x = hp0; hw.y = hp1;
            *(float2*)&houtb[i0] = hw;
        }
        __syncthreads();
    }

    // ---- project the last chunk
    {
        const int s  = tid & 3;
        const int cc = (tid >> 2) & 1;
        const int tl = tid >> 3;
        if (tl < CHUNK) {
            const float* hr = &houtb[(tl + 1) * HPAD + s * 32];
            float acc = 0.f;
            #pragma unroll
            for (int jj = 0; jj < 8; jj++) {
                int mm = 4 * ((jj + 2 * s) & 7);
                float4 hv = *(const float4*)(hr + mm);
                int k = s * 32 + mm;
                acc = fmaf(hv.x, wps[(k+0)*2 + cc],
                      fmaf(hv.y, wps[(k+1)*2 + cc],
                      fmaf(hv.z, wps[(k+2)*2 + cc],
                      fmaf(hv.w, wps[(k+3)*2 + cc], acc))));
            }
            acc = dpp_add<DPP_XOR1>(acc);
            acc = dpp_add<DPP_XOR2>(acc);
            if (s == 0)
                outb[((NCH - 1) * CHUNK + tl) * 2 + cc] = acc + wps[2 * RHH + cc];
        }
    }
}

extern "C" void kernel_launch(void* const* d_in, const int* in_sizes, int n_in,
                              void* d_out, int out_size, void* d_ws, size_t ws_size,
                              hipStream_t stream)
{
    const float* x      = (const float*)d_in[0];
    const int*   eidx   = (const int*)d_in[1];
    const int*   runner = (const int*)d_in[2];
    const float* W1     = (const float*)d_in[3];
    const float* b1     = (const float*)d_in[4];
    const float* W2     = (const float*)d_in[5];
    const float* b2     = (const float*)d_in[6];
    const float* W_ih   = (const float*)d_in[7];
    const float* W_hh   = (const float*)d_in[8];
    const float* b_ih   = (const float*)d_in[9];
    const float* b_hh   = (const float*)d_in[10];
    const float* Wp     = (const float*)d_in[11];
    const float* bp     = (const float*)d_in[12];
    float* out = (float*)d_out;

    float* xg  = (float*)d_ws;                       // 8192*384
    float* WTp = xg + (size_t)GG * 3 * RHH;          // packed W_ih

    pack_wih<<<192, 256, 0, stream>>>(W_ih, WTp);
    gcn_hsum<<<GG, 256, 0, stream>>>(x, eidx, runner, W1, b1, xg);
    seqxg_kernel<<<GG / 16, 384, 0, stream>>>(xg, W2, b2, WTp, b_ih);
    gru_kernel<<<BBB, 512, 0, stream>>>(xg, W_hh, b_hh, Wp, bp, out);
}